// Round 8
// baseline (374.450 us; speedup 1.0000x reference)
//
#include <hip/hip_runtime.h>

constexpr int IN_F   = 32;
constexpr int OUT_F  = 128;
constexpr int BLOCK  = 256;
constexpr int WAVES  = BLOCK / 64;
constexpr int RSTAGE = 8;          // rows per stage

using f32x2  = __attribute__((ext_vector_type(2)))  float;
using f32x16 = __attribute__((ext_vector_type(16))) float;

// After swap32(P,Q): P+Q gives lanes 0-31 the full (both-half) sum of P,
// lanes 32-63 the full sum of Q.  (Validated on HW in round 6.)
__device__ __forceinline__ void swap32(float& a, float& b) {
    asm volatile("v_permlane32_swap_b32 %0, %1" : "+v"(a), "+v"(b));
}

__global__ __launch_bounds__(BLOCK, 4)
void rbf_kernel(const float* __restrict__ x,
                const float* __restrict__ centres,
                const float* __restrict__ log_sigmas,
                float* __restrict__ out,
                int rows_per_wave)
{
    __shared__ float4 xs[WAVES][2][RSTAGE][IN_F / 4];   // 8 KB
    __shared__ float  x2s[WAVES][2][RSTAGE];

    const int tid  = threadIdx.x;
    const int wv   = tid >> 6;
    const int lane = tid & 63;
    const int j    = lane & 31;
    const int h    = lane >> 5;     // k-half this lane owns

    // ---- half-centres for outputs 4j..4j+3, k in [16h,16h+16), named vecs ----
    const float* cb = centres + (size_t)(4 * j) * IN_F + 16 * h;
    const f32x16 cA = *reinterpret_cast<const f32x16*>(cb + 0 * IN_F);
    const f32x16 cB = *reinterpret_cast<const f32x16*>(cb + 1 * IN_F);
    const f32x16 cC = *reinterpret_cast<const f32x16*>(cb + 2 * IN_F);
    const f32x16 cD = *reinterpret_cast<const f32x16*>(cb + 3 * IN_F);

    float q0 = 0.f, q1 = 0.f, q2 = 0.f, q3 = 0.f;
    #pragma unroll
    for (int k = 0; k < 16; ++k) {
        q0 = fmaf(cA[k], cA[k], q0);
        q1 = fmaf(cB[k], cB[k], q1);
        q2 = fmaf(cC[k], cC[k], q2);
        q3 = fmaf(cD[k], cD[k], q3);
    }
    // full ||c||^2 (own half + partner half), same value on both lane-halves
    float ta, tb;
    ta = q0; tb = q0; swap32(ta, tb); const float c20 = ta + tb;
    ta = q1; tb = q1; swap32(ta, tb); const float c21 = ta + tb;
    ta = q2; tb = q2; swap32(ta, tb); const float c22 = ta + tb;
    ta = q3; tb = q3; swap32(ta, tb); const float c23 = ta + tb;

    const float4 ls4 = *reinterpret_cast<const float4*>(log_sigmas + 4 * j);
    const float iv0 = __expf(-2.0f * ls4.x);
    const float iv1 = __expf(-2.0f * ls4.y);
    const float iv2 = __expf(-2.0f * ls4.z);
    const float iv3 = __expf(-2.0f * ls4.w);

    const size_t waveRow0 = ((size_t)blockIdx.x * WAVES + wv) * (size_t)rows_per_wave;
    const float* xb = x   + waveRow0 * IN_F;
    float*       ob = out + waveRow0 * OUT_F + 4 * j;

    const int rs = lane >> 3;       // staging: row this lane loads
    const int q  = lane & 7;        // staging: float4 slot
    const int nst = rows_per_wave / RSTAGE;

    // ---- 2-stage-deep register prefetch ----
    float4 vcur = *reinterpret_cast<const float4*>(xb + (size_t)rs * IN_F + q * 4);
    float4 vnxt = *reinterpret_cast<const float4*>(xb + (size_t)(RSTAGE + rs) * IN_F + q * 4);

    for (int s = 0; s < nst; ++s) {
        const int buf = s & 1;

        // ---- stage: ds_write 8 rows + ||x||^2 via shuffles (wave-private) ----
        float ss = vcur.x * vcur.x;
        ss = fmaf(vcur.y, vcur.y, ss);
        ss = fmaf(vcur.z, vcur.z, ss);
        ss = fmaf(vcur.w, vcur.w, ss);
        ss += __shfl_xor(ss, 1);
        ss += __shfl_xor(ss, 2);
        ss += __shfl_xor(ss, 4);
        xs[wv][buf][rs][q] = vcur;
        if (q == 0) x2s[wv][buf][rs] = ss;
        asm volatile("s_waitcnt lgkmcnt(0)" ::: "memory");
        __builtin_amdgcn_sched_barrier(0);

        vcur = vnxt;
        if (s + 2 < nst)
            vnxt = *reinterpret_cast<const float4*>(
                xb + (size_t)((s + 2) * RSTAGE + rs) * IN_F + q * 4);

        // ---- compute 4 micro-steps (2 rows each), collect results ----
        float4 rr[4];
        #pragma unroll
        for (int m = 0; m < 4; ++m) {
            f32x2 pA0 = {0.f,0.f}, pA1 = {0.f,0.f}, pA2 = {0.f,0.f}, pA3 = {0.f,0.f};
            f32x2 pB0 = {0.f,0.f}, pB1 = {0.f,0.f}, pB2 = {0.f,0.f}, pB3 = {0.f,0.f};
            #pragma unroll
            for (int u = 0; u < 4; ++u) {
                const float4 xa = xs[wv][buf][2*m + 0][h * 4 + u];  // 2-way bcast
                const float4 xv = xs[wv][buf][2*m + 1][h * 4 + u];
                const f32x2 ea0 = {xa.x, xa.y}, ea1 = {xa.z, xa.w};
                const f32x2 eb0 = {xv.x, xv.y}, eb1 = {xv.z, xv.w};
                const f32x2 cA0 = {cA[4*u+0], cA[4*u+1]}, cA1 = {cA[4*u+2], cA[4*u+3]};
                const f32x2 cB0 = {cB[4*u+0], cB[4*u+1]}, cB1 = {cB[4*u+2], cB[4*u+3]};
                const f32x2 cC0 = {cC[4*u+0], cC[4*u+1]}, cC1 = {cC[4*u+2], cC[4*u+3]};
                const f32x2 cD0 = {cD[4*u+0], cD[4*u+1]}, cD1 = {cD[4*u+2], cD[4*u+3]};
                pA0 = __builtin_elementwise_fma(ea0, cA0, pA0);
                pA0 = __builtin_elementwise_fma(ea1, cA1, pA0);
                pA1 = __builtin_elementwise_fma(ea0, cB0, pA1);
                pA1 = __builtin_elementwise_fma(ea1, cB1, pA1);
                pA2 = __builtin_elementwise_fma(ea0, cC0, pA2);
                pA2 = __builtin_elementwise_fma(ea1, cC1, pA2);
                pA3 = __builtin_elementwise_fma(ea0, cD0, pA3);
                pA3 = __builtin_elementwise_fma(ea1, cD1, pA3);
                pB0 = __builtin_elementwise_fma(eb0, cA0, pB0);
                pB0 = __builtin_elementwise_fma(eb1, cA1, pB0);
                pB1 = __builtin_elementwise_fma(eb0, cB0, pB1);
                pB1 = __builtin_elementwise_fma(eb1, cB1, pB1);
                pB2 = __builtin_elementwise_fma(eb0, cC0, pB2);
                pB2 = __builtin_elementwise_fma(eb1, cC1, pB2);
                pB3 = __builtin_elementwise_fma(eb0, cD0, pB3);
                pB3 = __builtin_elementwise_fma(eb1, cD1, pB3);
            }
            // combine halves: lower lanes -> full row-A dots, upper -> row-B
            float sA0 = pA0.x + pA0.y, sB0 = pB0.x + pB0.y;
            float sA1 = pA1.x + pA1.y, sB1 = pB1.x + pB1.y;
            float sA2 = pA2.x + pA2.y, sB2 = pB2.x + pB2.y;
            float sA3 = pA3.x + pA3.y, sB3 = pB3.x + pB3.y;
            swap32(sA0, sB0); const float d0 = sA0 + sB0;
            swap32(sA1, sB1); const float d1 = sA1 + sB1;
            swap32(sA2, sB2); const float d2 = sA2 + sB2;
            swap32(sA3, sB3); const float d3 = sA3 + sB3;

            const float x2v = x2s[wv][buf][2*m + h];   // my row's ||x||^2
            const float t0 = fmaxf(fmaf(-2.0f, d0, x2v + c20), 0.0f);
            const float t1 = fmaxf(fmaf(-2.0f, d1, x2v + c21), 0.0f);
            const float t2 = fmaxf(fmaf(-2.0f, d2, x2v + c22), 0.0f);
            const float t3 = fmaxf(fmaf(-2.0f, d3, x2v + c23), 0.0f);
            float4 o4;
            o4.x = __expf(-t0 * iv0);
            o4.y = __expf(-t1 * iv1);
            o4.z = __expf(-t2 * iv2);
            o4.w = __expf(-t3 * iv3);
            rr[m] = o4;
        }

        // ---- burst: 4 × dwordx4 stores, each covers 2 full rows (1 KB/wave) ----
        float* os = ob + (size_t)(s * RSTAGE + h) * OUT_F;
        #pragma unroll
        for (int m = 0; m < 4; ++m)
            *reinterpret_cast<float4*>(os + (size_t)(2 * m) * OUT_F) = rr[m];
    }
}

extern "C" void kernel_launch(void* const* d_in, const int* in_sizes, int n_in,
                              void* d_out, int out_size, void* d_ws, size_t ws_size,
                              hipStream_t stream) {
    const float* x          = (const float*)d_in[0];
    const float* centres    = (const float*)d_in[1];
    const float* log_sigmas = (const float*)d_in[2];
    float* out = (float*)d_out;

    const int n = in_sizes[0] / IN_F;                   // 1,048,576 rows
    const int blocks = 4096;
    const int rows_per_wave = n / (blocks * WAVES);     // 64 (8 stages of 8)
    rbf_kernel<<<blocks, BLOCK, 0, stream>>>(x, centres, log_sigmas, out, rows_per_wave);
}

// Round 9
// 172.711 us; speedup vs baseline: 2.1681x; 2.1681x over previous
//
#include <hip/hip_runtime.h>

constexpr int IN_F   = 32;
constexpr int OUT_F  = 128;
constexpr int BLOCK  = 256;
constexpr int WAVES  = BLOCK / 64;
constexpr int RSTAGE = 8;          // rows staged per wave per iteration

using f32x16 = __attribute__((ext_vector_type(16))) float;

// After swap32(a,b): lane l<32: a=a_orig[l], b=a_orig[l+32];
//                    lane l>=32: a=b_orig[l-32], b=b_orig[l].
// So a+b = full (both-half) sum of a_orig on lanes 0-31, of b_orig on 32-63.
// (Validated on HW in rounds 6/8.)
__device__ __forceinline__ void swap32(float& a, float& b) {
    asm volatile("v_permlane32_swap_b32 %0, %1" : "+v"(a), "+v"(b));
}

__global__ __launch_bounds__(BLOCK, 2)
void rbf_kernel(const float* __restrict__ x,
                const float* __restrict__ centres,
                const float* __restrict__ log_sigmas,
                float* __restrict__ out,
                int rows_per_wave)
{
    __shared__ float4 xs[WAVES][RSTAGE][IN_F / 4];
    __shared__ float  x2s[WAVES][RSTAGE];

    const int tid  = threadIdx.x;
    const int wv   = tid >> 6;
    const int lane = tid & 63;
    const int j    = lane & 31;
    const int h    = lane >> 5;     // k-half this lane owns

    // ---- half-centres for outputs 4j..4j+3, k in [16h,16h+16), named vecs ----
    const float* cb = centres + (size_t)(4 * j) * IN_F + 16 * h;
    const f32x16 cA = *reinterpret_cast<const f32x16*>(cb + 0 * IN_F);
    const f32x16 cB = *reinterpret_cast<const f32x16*>(cb + 1 * IN_F);
    const f32x16 cC = *reinterpret_cast<const f32x16*>(cb + 2 * IN_F);
    const f32x16 cD = *reinterpret_cast<const f32x16*>(cb + 3 * IN_F);

    float q0 = 0.f, q1 = 0.f, q2 = 0.f, q3 = 0.f;
    #pragma unroll
    for (int k = 0; k < 16; ++k) {
        q0 = fmaf(cA[k], cA[k], q0);
        q1 = fmaf(cB[k], cB[k], q1);
        q2 = fmaf(cC[k], cC[k], q2);
        q3 = fmaf(cD[k], cD[k], q3);
    }
    float ta, tb;
    ta = q0; tb = q0; swap32(ta, tb); const float c20 = ta + tb;
    ta = q1; tb = q1; swap32(ta, tb); const float c21 = ta + tb;
    ta = q2; tb = q2; swap32(ta, tb); const float c22 = ta + tb;
    ta = q3; tb = q3; swap32(ta, tb); const float c23 = ta + tb;

    const float4 ls4 = *reinterpret_cast<const float4*>(log_sigmas + 4 * j);
    const float iv0 = __expf(-2.0f * ls4.x);
    const float iv1 = __expf(-2.0f * ls4.y);
    const float iv2 = __expf(-2.0f * ls4.z);
    const float iv3 = __expf(-2.0f * ls4.w);

    const size_t waveRow0 = ((size_t)blockIdx.x * WAVES + wv) * (size_t)rows_per_wave;
    const int rs = lane >> 3;       // staging: row this lane loads
    const int q  = lane & 7;        // staging: float4 slot

    for (int it = 0; it < rows_per_wave; it += RSTAGE) {
        // ---- stage 8 rows: one coalesced 1 KB load per wave ----
        const float4 v = *reinterpret_cast<const float4*>(
            x + (waveRow0 + it) * IN_F + lane * 4);
        float ss = v.x * v.x;
        ss = fmaf(v.y, v.y, ss);
        ss = fmaf(v.z, v.z, ss);
        ss = fmaf(v.w, v.w, ss);
        ss += __shfl_xor(ss, 1);
        ss += __shfl_xor(ss, 2);
        ss += __shfl_xor(ss, 4);
        xs[wv][rs][q] = v;
        if (q == 0) x2s[wv][rs] = ss;
        __syncthreads();

        // ---- 4 micro-steps of 2 rows; one 1 KB dwordx4 store per step ----
        #pragma unroll
        for (int m = 0; m < 4; ++m) {
            float pA0 = 0.f, pA1 = 0.f, pA2 = 0.f, pA3 = 0.f;
            float pB0 = 0.f, pB1 = 0.f, pB2 = 0.f, pB3 = 0.f;
            #pragma unroll
            for (int u = 0; u < 4; ++u) {
                // my k-half of both rows: 2 distinct addrs/wave -> broadcast
                const float4 xa = xs[wv][2*m + 0][h * 4 + u];
                const float4 xv = xs[wv][2*m + 1][h * 4 + u];
                pA0 = fmaf(xa.x, cA[4*u+0], pA0); pA0 = fmaf(xa.y, cA[4*u+1], pA0);
                pA0 = fmaf(xa.z, cA[4*u+2], pA0); pA0 = fmaf(xa.w, cA[4*u+3], pA0);
                pA1 = fmaf(xa.x, cB[4*u+0], pA1); pA1 = fmaf(xa.y, cB[4*u+1], pA1);
                pA1 = fmaf(xa.z, cB[4*u+2], pA1); pA1 = fmaf(xa.w, cB[4*u+3], pA1);
                pA2 = fmaf(xa.x, cC[4*u+0], pA2); pA2 = fmaf(xa.y, cC[4*u+1], pA2);
                pA2 = fmaf(xa.z, cC[4*u+2], pA2); pA2 = fmaf(xa.w, cC[4*u+3], pA2);
                pA3 = fmaf(xa.x, cD[4*u+0], pA3); pA3 = fmaf(xa.y, cD[4*u+1], pA3);
                pA3 = fmaf(xa.z, cD[4*u+2], pA3); pA3 = fmaf(xa.w, cD[4*u+3], pA3);
                pB0 = fmaf(xv.x, cA[4*u+0], pB0); pB0 = fmaf(xv.y, cA[4*u+1], pB0);
                pB0 = fmaf(xv.z, cA[4*u+2], pB0); pB0 = fmaf(xv.w, cA[4*u+3], pB0);
                pB1 = fmaf(xv.x, cB[4*u+0], pB1); pB1 = fmaf(xv.y, cB[4*u+1], pB1);
                pB1 = fmaf(xv.z, cB[4*u+2], pB1); pB1 = fmaf(xv.w, cB[4*u+3], pB1);
                pB2 = fmaf(xv.x, cC[4*u+0], pB2); pB2 = fmaf(xv.y, cC[4*u+1], pB2);
                pB2 = fmaf(xv.z, cC[4*u+2], pB2); pB2 = fmaf(xv.w, cC[4*u+3], pB2);
                pB3 = fmaf(xv.x, cD[4*u+0], pB3); pB3 = fmaf(xv.y, cD[4*u+1], pB3);
                pB3 = fmaf(xv.z, cD[4*u+2], pB3); pB3 = fmaf(xv.w, cD[4*u+3], pB3);
            }
            // combine halves: lanes 0-31 -> row 2m full dots, 32-63 -> row 2m+1
            swap32(pA0, pB0); const float d0 = pA0 + pB0;
            swap32(pA1, pB1); const float d1 = pA1 + pB1;
            swap32(pA2, pB2); const float d2 = pA2 + pB2;
            swap32(pA3, pB3); const float d3 = pA3 + pB3;

            const float x2v = x2s[wv][2*m + h];       // my row's ||x||^2
            const float t0 = fmaxf(fmaf(-2.0f, d0, x2v + c20), 0.0f);
            const float t1 = fmaxf(fmaf(-2.0f, d1, x2v + c21), 0.0f);
            const float t2 = fmaxf(fmaf(-2.0f, d2, x2v + c22), 0.0f);
            const float t3 = fmaxf(fmaf(-2.0f, d3, x2v + c23), 0.0f);
            float4 o4;
            o4.x = __expf(-t0 * iv0);
            o4.y = __expf(-t1 * iv1);
            o4.z = __expf(-t2 * iv2);
            o4.w = __expf(-t3 * iv3);
            // lanes 0-31 cover row 2m (512 B), lanes 32-63 row 2m+1: 1 KB/instr
            *reinterpret_cast<float4*>(
                out + (waveRow0 + it + 2*m + h) * OUT_F + 4 * j) = o4;
        }
        __syncthreads();           // protect xs before next stage overwrites
    }
}

extern "C" void kernel_launch(void* const* d_in, const int* in_sizes, int n_in,
                              void* d_out, int out_size, void* d_ws, size_t ws_size,
                              hipStream_t stream) {
    const float* x          = (const float*)d_in[0];
    const float* centres    = (const float*)d_in[1];
    const float* log_sigmas = (const float*)d_in[2];
    float* out = (float*)d_out;

    const int n = in_sizes[0] / IN_F;                   // 1,048,576 rows
    const int blocks = 2048;
    const int rows_per_block = n / blocks;              // 512
    const int rows_per_wave  = rows_per_block / WAVES;  // 128 (16 stages of 8)
    rbf_kernel<<<blocks, BLOCK, 0, stream>>>(x, centres, log_sigmas, out, rows_per_wave);
}

// Round 10
// 153.323 us; speedup vs baseline: 2.4422x; 1.1265x over previous
//
#include <hip/hip_runtime.h>

constexpr int IN_F   = 32;
constexpr int OUT_F  = 128;
constexpr int BLOCK  = 256;
constexpr int WAVES  = BLOCK / 64;
constexpr int RSTAGE = 8;          // rows per wave per stage

using f32x2  = __attribute__((ext_vector_type(2)))  float;
using f32x16 = __attribute__((ext_vector_type(16))) float;

__global__ __launch_bounds__(BLOCK, 4)
void rbf_kernel(const float* __restrict__ x,
                const float* __restrict__ centres,
                const float* __restrict__ log_sigmas,
                float* __restrict__ out,
                int nstages, int stage_rows)
{
    __shared__ float4 xs[WAVES][RSTAGE][IN_F / 4];
    __shared__ float  x2s[WAVES][RSTAGE];

    const int tid  = threadIdx.x;
    const int wv   = tid >> 6;
    const int lane = tid & 63;

    // ---- centres for outputs 2*lane, 2*lane+1 as NAMED f32x16 values ----
    const int o0 = lane * 2;
    const f32x16 c0lo = *reinterpret_cast<const f32x16*>(centres + (size_t)(o0 + 0) * IN_F);
    const f32x16 c0hi = *reinterpret_cast<const f32x16*>(centres + (size_t)(o0 + 0) * IN_F + 16);
    const f32x16 c1lo = *reinterpret_cast<const f32x16*>(centres + (size_t)(o0 + 1) * IN_F);
    const f32x16 c1hi = *reinterpret_cast<const f32x16*>(centres + (size_t)(o0 + 1) * IN_F + 16);

    float c2a = 0.f, c2b = 0.f;
    #pragma unroll
    for (int k = 0; k < 16; ++k) {
        c2a = fmaf(c0lo[k], c0lo[k], c2a);
        c2a = fmaf(c0hi[k], c0hi[k], c2a);
        c2b = fmaf(c1lo[k], c1lo[k], c2b);
        c2b = fmaf(c1hi[k], c1hi[k], c2b);
    }
    const float iv0 = __expf(-2.0f * log_sigmas[o0 + 0]);
    const float iv1 = __expf(-2.0f * log_sigmas[o0 + 1]);

    // global wave id: adjacent waves own adjacent 8-row (4 KB) output chunks,
    // and the whole GPU sweeps one contiguous row window per stage.
    const int gw = blockIdx.x * WAVES + wv;
    const int rs = lane >> 3;      // staging: row this lane loads
    const int q  = lane & 7;       // staging: float4 slot

    for (int s = 0; s < nstages; ++s) {
        const size_t row0 = (size_t)s * stage_rows + (size_t)gw * RSTAGE;

        // ---- stage 8 rows: one coalesced 1 KB load per wave ----
        const float4 v = *reinterpret_cast<const float4*>(
            x + row0 * IN_F + lane * 4);
        float ss = v.x * v.x;
        ss = fmaf(v.y, v.y, ss);
        ss = fmaf(v.z, v.z, ss);
        ss = fmaf(v.w, v.w, ss);
        ss += __shfl_xor(ss, 1);
        ss += __shfl_xor(ss, 2);
        ss += __shfl_xor(ss, 4);   // lanes sharing rs now hold full ||x||^2
        xs[wv][rs][q] = v;
        if (q == 0) x2s[wv][rs] = ss;
        __syncthreads();

        #pragma unroll
        for (int rr = 0; rr < RSTAGE; ++rr) {
            float acc0 = 0.f, acc1 = 0.f;
            #pragma unroll
            for (int u = 0; u < 4; ++u) {
                const float4 xq = xs[wv][rr][u];          // wave-uniform: broadcast
                acc0 = fmaf(xq.x, c0lo[4*u+0], acc0);
                acc0 = fmaf(xq.y, c0lo[4*u+1], acc0);
                acc0 = fmaf(xq.z, c0lo[4*u+2], acc0);
                acc0 = fmaf(xq.w, c0lo[4*u+3], acc0);
                acc1 = fmaf(xq.x, c1lo[4*u+0], acc1);
                acc1 = fmaf(xq.y, c1lo[4*u+1], acc1);
                acc1 = fmaf(xq.z, c1lo[4*u+2], acc1);
                acc1 = fmaf(xq.w, c1lo[4*u+3], acc1);
            }
            #pragma unroll
            for (int u = 0; u < 4; ++u) {
                const float4 xq = xs[wv][rr][4 + u];
                acc0 = fmaf(xq.x, c0hi[4*u+0], acc0);
                acc0 = fmaf(xq.y, c0hi[4*u+1], acc0);
                acc0 = fmaf(xq.z, c0hi[4*u+2], acc0);
                acc0 = fmaf(xq.w, c0hi[4*u+3], acc0);
                acc1 = fmaf(xq.x, c1hi[4*u+0], acc1);
                acc1 = fmaf(xq.y, c1hi[4*u+1], acc1);
                acc1 = fmaf(xq.z, c1hi[4*u+2], acc1);
                acc1 = fmaf(xq.w, c1hi[4*u+3], acc1);
            }
            const float x2 = x2s[wv][rr];
            const float t0 = fmaxf(fmaf(-2.0f, acc0, x2 + c2a), 0.0f);
            const float t1 = fmaxf(fmaf(-2.0f, acc1, x2 + c2b), 0.0f);
            f32x2 o;
            o.x = __expf(-t0 * iv0);
            o.y = __expf(-t1 * iv1);
            // lane l writes bytes [8l, 8l+8): 512 B contiguous per wave per row
            __builtin_nontemporal_store(o,
                reinterpret_cast<f32x2*>(out + (row0 + rr) * OUT_F + o0));
        }
        __syncthreads();           // protect xs before next stage overwrites
    }
}

extern "C" void kernel_launch(void* const* d_in, const int* in_sizes, int n_in,
                              void* d_out, int out_size, void* d_ws, size_t ws_size,
                              hipStream_t stream) {
    const float* x          = (const float*)d_in[0];
    const float* centres    = (const float*)d_in[1];
    const float* log_sigmas = (const float*)d_in[2];
    float* out = (float*)d_out;

    const int n = in_sizes[0] / IN_F;                   // 1,048,576 rows
    const int blocks = 2048;
    const int stage_rows = blocks * WAVES * RSTAGE;     // 65536 rows per global stage
    const int nstages = n / stage_rows;                 // 16
    rbf_kernel<<<blocks, BLOCK, 0, stream>>>(x, centres, log_sigmas, out,
                                             nstages, stage_rows);
}